// Round 5
// baseline (21246.738 us; speedup 1.0000x reference)
//
#include <hip/hip_runtime.h>
#include <math.h>

#define T_STEPS 4096
#define RES     2048
#define NF      8
#define NR      8
#define K_WG    256      // one WG per CU; WG owns 8 cols (1 per wave)
#define REC_THR 512      // 8 waves
#define RO_THR  256
#define SENTINEL 2.0f    // reachable |x| < 1 strictly (|x|<=0.7|x|+0.3); 2.0 unreachable
#define XS_PAD  2304     // xs row stride: pads LDS to 82.4 KB -> exactly 1 WG/CU

// ---------------------------------------------------------------------------
// drive[t][j] = Win[0][j] + sum_f inp[t][f] * Win[1+f][j]
__global__ void k_drive(const float* __restrict__ inp, const float* __restrict__ Win,
                        float* __restrict__ drive) {
    int idx = blockIdx.x * blockDim.x + threadIdx.x;   // [0, T*RES)
    int t = idx >> 11;
    int j = idx & (RES - 1);
    float d = Win[j];
#pragma unroll
    for (int f = 0; f < NF; ++f)
        d += inp[t * NF + f] * Win[(1 + f) * RES + j];
    drive[idx] = d;
}

// ---------------------------------------------------------------------------
// X[0][:] = 0 (valid initial state); X[1..T][:] = SENTINEL (unwritten)
__global__ void k_init(float* __restrict__ X) {
    int tid = threadIdx.x + blockIdx.x * blockDim.x;
    int stride = blockDim.x * gridDim.x;
    const int total = (T_STEPS + 1) * RES;
    for (int i = tid; i < total; i += stride)
        X[i] = (i < RES) ? 0.f : SENTINEL;
}

// ---------------------------------------------------------------------------
// Persistent dataflow recurrence, W resident in LDS.
//  - Rounds 1-4 falsified register residency: allocator spills/re-streams any
//    loop-carried W array (VGPR_Count 84/112/76/60, FETCH up to 1 GB). LDS
//    residency is deterministic: W tile (2048x8 cols = 64 KB) transposed into
//    LDS once, read back with conflict-free ds_read_b128 every step.
//  - Wave w owns column c = 8k+w. Lane l handles rows {i*256 + 4l .. +4}.
//  - Sync (proven in R3/R4): sentinel-in-data. Wave 0 polls global row t
//    (agent-scope relaxed loads, predicated re-poll), stages into LDS
//    (double-buffered), releases LDS flag = t+1 (release drains the wave's
//    ds_writes via lgkmcnt(0)). Waves 1-7 spin on the flag (acquire), then
//    ds_read x. 2-buffer safety: wave0 stages row t+2 only after row t+2 is
//    globally complete, which requires this WG's waves to have finished step
//    t+1, hence consumed buffer (t&1) at step t.
//  - W ds_reads are issued BEFORE the flag spin (step-invariant data, asm
//    pin stops sinking) so their pipe cost hides under the sync wait.
__global__ __launch_bounds__(REC_THR, 2) void k_recur(
        const float* __restrict__ W, const float* __restrict__ drive,
        float* __restrict__ X) {
    __shared__ float    Wl[8][RES];        // 64 KB: Wl[cc][r] = W[r][8k+cc]
    __shared__ float    xs[2][XS_PAD];     // 18.4 KB (padded rows)
    __shared__ unsigned flag;              // monotonic: last staged step+1

    const int tid  = threadIdx.x;
    const int wave = tid >> 6;
    const int lane = tid & 63;
    const int c0   = blockIdx.x * 8;
    const int c    = c0 + wave;            // this wave's output column

    // One-time: transpose W tile into LDS (column-major per column).
    for (int idx = tid; idx < 8 * RES; idx += REC_THR) {
        int r = idx >> 3, cc = idx & 7;
        Wl[cc][r] = W[(size_t)r * RES + c0 + cc];
    }
    if (tid == 0) flag = 0;
    __syncthreads();   // one-time init barrier

    float xprev = 0.f;   // lane 0: own column's x_t (x_0 = 0)

    for (int t = 0; t < T_STEPS; ++t) {
        // Independent of x_t: drive for this wave's column.
        float dr = (lane == 0) ? drive[(size_t)t * RES + c] : 0.f;

        // Prefetch this wave's W column from LDS (step-invariant values);
        // asm pin forces materialization before the spin so the ds_read
        // throughput cost overlaps the sync wait.
        float4 wv[8];
#pragma unroll
        for (int i = 0; i < 8; ++i)
            wv[i] = *reinterpret_cast<const float4*>(&Wl[wave][i * 256 + 4 * lane]);
#pragma unroll
        for (int i = 0; i < 8; ++i)
            asm volatile("" : "+v"(wv[i].x), "+v"(wv[i].y), "+v"(wv[i].z), "+v"(wv[i].w));

        float a = 0.f;
        if (wave == 0) {
            const float* xrow = X + (size_t)t * RES;
            float xv[32];   // [i*4+j] = x[i*256 + 4*lane + j]
#pragma unroll
            for (int i = 0; i < 8; ++i)
#pragma unroll
                for (int j = 0; j < 4; ++j)
                    xv[i * 4 + j] = __hip_atomic_load(&xrow[i * 256 + 4 * lane + j],
                                                      __ATOMIC_RELAXED,
                                                      __HIP_MEMORY_SCOPE_AGENT);
            for (;;) {
                float m = 0.f;
#pragma unroll
                for (int k = 0; k < 32; ++k)
                    m = fmaxf(m, __builtin_fabsf(xv[k]));
                if (__all(m < 1.5f)) break;
                __builtin_amdgcn_s_sleep(1);
#pragma unroll
                for (int i = 0; i < 8; ++i)
#pragma unroll
                    for (int j = 0; j < 4; ++j)
                        if (__builtin_fabsf(xv[i * 4 + j]) > 1.5f)
                            xv[i * 4 + j] = __hip_atomic_load(
                                &xrow[i * 256 + 4 * lane + j],
                                __ATOMIC_RELAXED, __HIP_MEMORY_SCOPE_AGENT);
            }
            // Stage to LDS: 8 x ds_write_b128, conflict-free (16 B lane stride).
            float* dst = xs[t & 1];
#pragma unroll
            for (int i = 0; i < 8; ++i)
                *reinterpret_cast<float4*>(&dst[i * 256 + 4 * lane]) =
                    make_float4(xv[i * 4 + 0], xv[i * 4 + 1], xv[i * 4 + 2], xv[i * 4 + 3]);
            if (lane == 0)
                __hip_atomic_store(&flag, (unsigned)(t + 1),
                                   __ATOMIC_RELEASE, __HIP_MEMORY_SCOPE_WORKGROUP);
            // Compute from registers directly (skip LDS round-trip).
#pragma unroll
            for (int i = 0; i < 8; ++i) {
                a = fmaf(xv[i * 4 + 0], wv[i].x, a);
                a = fmaf(xv[i * 4 + 1], wv[i].y, a);
                a = fmaf(xv[i * 4 + 2], wv[i].z, a);
                a = fmaf(xv[i * 4 + 3], wv[i].w, a);
            }
        } else {
            while (__hip_atomic_load(&flag, __ATOMIC_ACQUIRE,
                                     __HIP_MEMORY_SCOPE_WORKGROUP) < (unsigned)(t + 1))
                __builtin_amdgcn_s_sleep(1);
            const float* src = xs[t & 1];
#pragma unroll
            for (int i = 0; i < 8; ++i) {
                float4 xq = *reinterpret_cast<const float4*>(&src[i * 256 + 4 * lane]);
                a = fmaf(xq.x, wv[i].x, a);
                a = fmaf(xq.y, wv[i].y, a);
                a = fmaf(xq.z, wv[i].z, a);
                a = fmaf(xq.w, wv[i].w, a);
            }
        }

        // 64-lane butterfly: lane 0 ends with the full column sum.
#pragma unroll
        for (int off = 32; off >= 1; off >>= 1)
            a += __shfl_xor(a, off, 64);

        if (lane == 0) {
            float xn = 0.7f * xprev + 0.3f * tanhf(dr + a);
            xprev = xn;
            __hip_atomic_store(&X[(size_t)(t + 1) * RES + c], xn,
                               __ATOMIC_RELAXED, __HIP_MEMORY_SCOPE_AGENT);
        }
    }
}

// ---------------------------------------------------------------------------
// Y[t][r] = Wout[0][r] + sum_f inp[t][f]*Wout[1+f][r] + sum_j X[t+1][j]*Wout[9+j][r]
__global__ void k_readout(const float* __restrict__ inp, const float* __restrict__ Wout,
                          const float* __restrict__ X, float* __restrict__ Y) {
    int t   = blockIdx.x;
    int tid = threadIdx.x;
    int r   = tid & (NR - 1);
    int gph = tid >> 3;                    // 32 groups
    const float* x = X + (size_t)(t + 1) * RES;
    float p = 0.f;
#pragma unroll 4
    for (int m = 0; m < RES / 32; ++m) {
        int j = gph * (RES / 32) + m;
        p += x[j] * Wout[(size_t)(1 + NF + j) * NR + r];
    }
    __shared__ float red[RO_THR];
    red[tid] = p;
    __syncthreads();
    for (int s = RO_THR / 2; s >= NR; s >>= 1) {
        if (tid < s) red[tid] += red[tid + s];
        __syncthreads();
    }
    if (tid < NR) {
        float y = Wout[tid];
#pragma unroll
        for (int f = 0; f < NF; ++f)
            y += inp[t * NF + f] * Wout[(1 + f) * NR + tid];
        Y[t * NR + tid] = y + red[tid];
    }
}

// ---------------------------------------------------------------------------
extern "C" void kernel_launch(void* const* d_in, const int* in_sizes, int n_in,
                              void* d_out, int out_size, void* d_ws, size_t ws_size,
                              hipStream_t stream) {
    const float* inp  = (const float*)d_in[0];   // (T, 8)
    const float* Win  = (const float*)d_in[1];   // (9, 2048)
    const float* W    = (const float*)d_in[2];   // (2048, 2048)
    const float* Wout = (const float*)d_in[3];   // (2057, 8)
    float* Y = (float*)d_out;                    // (T, 8)

    float* drive = (float*)d_ws;                            // 32 MB
    float* X     = drive + (size_t)T_STEPS * RES;           // 32 MB + 8 KB

    k_init<<<2048, 256, 0, stream>>>(X);
    k_drive<<<(T_STEPS * RES) / 256, 256, 0, stream>>>(inp, Win, drive);
    k_recur<<<K_WG, REC_THR, 0, stream>>>(W, drive, X);
    k_readout<<<T_STEPS, RO_THR, 0, stream>>>(inp, Wout, X, Y);
}